// Round 1
// baseline (1322.634 us; speedup 1.0000x reference)
//
#include <hip/hip_runtime.h>

#define TW_STEP 0.09817477042468103f  // 2*pi/64

// ---------------- workspace layout (bytes) ----------------
static constexpr size_t SZ_P   = (size_t)4*32*64*64*64*4;   // 134217728  field P [B][C][X][Y][Z] fp32
static constexpr size_t SZ_A   = (size_t)4*32*8*64*64*8;    // 33554432   T1 [b][c][kz][x][y] f2  /  U2 [b][kz][x][y][o] f2
static constexpr size_t SZ_B2  = (size_t)4*32*8*16*64*8;    // 8388608    T2 [b][c][kz][kyi][x] f2 / U1 [b][o][kz][x][kyi] f2
static constexpr size_t SZ_XF  = (size_t)4*32*8*16*16*8;    // 2097152    Xf / Yf [b][c][kz][kyi][kxi] f2
static constexpr size_t OFF_P  = 0;
static constexpr size_t OFF_A  = OFF_P + SZ_P;
static constexpr size_t OFF_B2 = OFF_A + SZ_A;
static constexpr size_t OFF_XF = OFF_B2 + SZ_B2;
static constexpr size_t OFF_YF = OFF_XF + SZ_XF;
static constexpr size_t OFF_PART = OFF_YF + SZ_XF;          // 32*16*2 floats = 4KB
static constexpr size_t OFF_TW  = OFF_PART + 4096;          // 64 float2
static constexpr size_t OFF_BNP = OFF_TW + 512;             // 4 layers * 64 floats

// ---------------- kernels ----------------

__global__ void k_twinit(float2* tw) {
    int t = threadIdx.x;
    if (t < 64) { float s, c; sincosf(TW_STEP * t, &s, &c); tw[t] = make_float2(c, s); }
}

// lift: x[B,X,Y,Z,3] -> P[b][w][x][y][z]
__global__ __launch_bounds__(256) void k_lift(const float* __restrict__ x,
                                              const float* __restrict__ w,
                                              const float* __restrict__ bias,
                                              float* __restrict__ P) {
    int v = blockIdx.x * 256 + threadIdx.x;      // 1048576 voxels
    int z = v & 63, y = (v >> 6) & 63, xx = (v >> 12) & 63, b = v >> 18;
    float i0 = x[(size_t)v * 3 + 0], i1 = x[(size_t)v * 3 + 1], i2 = x[(size_t)v * 3 + 2];
#pragma unroll
    for (int c = 0; c < 32; c++) {
        float val = bias[c] + w[c * 3 + 0] * i0 + w[c * 3 + 1] * i1 + w[c * 3 + 2] * i2;
        P[(size_t)(((b * 32 + c) * 64 + xx) * 64 + y) * 64 + z] = val;
    }
}

// forward z-DFT: P (with on-the-fly bn+relu) -> T1[b][c][kz][x][y], raw sums e^{-i}
__global__ __launch_bounds__(256) void k_zfwd(const float* __restrict__ P,
                                              const float2* __restrict__ gtw,
                                              const float* __restrict__ bnp, int relu,
                                              float2* __restrict__ T1) {
    int g = blockIdx.x * 256 + threadIdx.x;      // 524288 = (b,c,x,y)
    int y = g & 63, x = (g >> 6) & 63, c = (g >> 12) & 31, b = g >> 17;
    float sc = 1.f, sh = 0.f;
    if (bnp) { sc = bnp[c]; sh = bnp[32 + c]; }
    const float* row = P + (size_t)(((b * 32 + c) * 64 + x) * 64 + y) * 64;
    float ar[8], ai[8];
#pragma unroll
    for (int k = 0; k < 8; k++) { ar[k] = 0.f; ai[k] = 0.f; }
#pragma unroll
    for (int q = 0; q < 16; q++) {
        float4 v4 = ((const float4*)row)[q];
        float vv[4] = {v4.x, v4.y, v4.z, v4.w};
#pragma unroll
        for (int j = 0; j < 4; j++) {
            float v = vv[j] * sc + sh;
            if (relu) v = fmaxf(v, 0.f);
            int z = q * 4 + j;
#pragma unroll
            for (int k = 0; k < 8; k++) {
                float2 t = gtw[(k * z) & 63];
                ar[k] = fmaf(v, t.x, ar[k]);
                ai[k] = fmaf(-v, t.y, ai[k]);
            }
        }
    }
    int ob = ((b * 32 + c) * 8) * 4096 + x * 64 + y;
#pragma unroll
    for (int k = 0; k < 8; k++) T1[ob + k * 4096] = make_float2(ar[k], ai[k]);
}

// generic forward 64->16 complex DFT along contiguous rows.
// mode 0 (y-stage): t=(b,c,kz,x); out[(t>>6)*1024 + ki*64 + (t&63)]
// mode 1 (x-stage): t=(b,c,kz,kyi); out[t*16 + ki]
__global__ __launch_bounds__(256) void k_dftf(const float2* __restrict__ in,
                                              float2* __restrict__ out,
                                              const float2* __restrict__ gtw,
                                              int n, int mode) {
    int t = blockIdx.x * 256 + threadIdx.x;
    if (t >= n) return;
    const float2* row = in + (size_t)t * 64;
    float ar[16], ai[16];
#pragma unroll
    for (int k = 0; k < 16; k++) { ar[k] = 0.f; ai[k] = 0.f; }
    for (int y = 0; y < 64; y++) {
        float2 v = row[y];
#pragma unroll
        for (int ki = 0; ki < 16; ki++) {
            int f = ki < 8 ? ki : ki + 48;
            float2 tw = gtw[(f * y) & 63];
            ar[ki] += v.x * tw.x + v.y * tw.y;   // (vr+ivi)(c - i s)
            ai[ki] += v.y * tw.x - v.x * tw.y;
        }
    }
    if (mode == 0) {
        int base = (t >> 6) * 1024 + (t & 63);
#pragma unroll
        for (int ki = 0; ki < 16; ki++) out[base + ki * 64] = make_float2(ar[ki], ai[ki]);
    } else {
#pragma unroll
        for (int ki = 0; ki < 16; ki++) out[t * 16 + ki] = make_float2(ar[ki], ai[ki]);
    }
}

// spectral multiply: Yf[b][o][m] = (1/64^3) * sum_i Xf[b][i][m] * w[corner][i][o][modes]
__global__ __launch_bounds__(128) void k_specmul(const float2* __restrict__ Xf,
                                                 const float* __restrict__ swl,
                                                 float2* __restrict__ Yf) {
    int m = blockIdx.x;                           // 2048 = (kz,kyi,kxi)
    int kxi = m & 15, kyi = (m >> 4) & 15, kz = m >> 8;
    int corner = (kxi >= 8 ? 1 : 0) + (kyi >= 8 ? 2 : 0);
    int mx = kxi & 7, my = kyi & 7;
    __shared__ float2 wsd[1024];
    __shared__ float2 xfs[128];
    int tid = threadIdx.x;
    const float* wb = swl + (size_t)corner * 1048576 + mx * 128 + my * 16 + kz * 2;
    for (int idx = tid; idx < 1024; idx += 128) {
        int i = idx >> 5, o = idx & 31;
        const float* p = wb + (size_t)i * 32768 + o * 1024;
        wsd[idx] = make_float2(p[0], p[1]);
    }
    {
        int b = tid >> 5, i = tid & 31;
        xfs[tid] = Xf[(((b * 32 + i) * 8 + kz) * 16 + kyi) * 16 + kxi];
    }
    __syncthreads();
    int b = tid >> 5, o = tid & 31;
    float ar = 0.f, ai = 0.f;
#pragma unroll
    for (int i = 0; i < 32; i++) {
        float2 xv = xfs[b * 32 + i];
        float2 wv = wsd[i * 32 + o];
        ar += xv.x * wv.x - xv.y * wv.y;
        ai += xv.x * wv.y + xv.y * wv.x;
    }
    const float s = 1.0f / 262144.0f;
    Yf[(((b * 32 + o) * 8 + kz) * 16 + kyi) * 16 + kxi] = make_float2(ar * s, ai * s);
}

// inverse x: U1[b][o][kz][x][kyi] = sum_kx Yf * e^{+i}
__global__ __launch_bounds__(256) void k_xinv(const float2* __restrict__ Yf,
                                              float2* __restrict__ U1) {
    int blk = blockIdx.x;                         // 1024 = (b,o,kz)
    int kz = blk & 7, o = (blk >> 3) & 31, b = blk >> 8;
    __shared__ float2 yfs[16][17];
    __shared__ float2 tw[64];
    int tid = threadIdx.x;
    if (tid < 64) { float s, c; sincosf(TW_STEP * tid, &s, &c); tw[tid] = make_float2(c, s); }
    {
        int kyi = tid >> 4, kxi = tid & 15;
        yfs[kyi][kxi] = Yf[(size_t)((b * 32 + o) * 8 + kz) * 256 + tid];
    }
    __syncthreads();
    int base = ((b * 32 + o) * 8 + kz) * 1024;
#pragma unroll
    for (int r = 0; r < 4; r++) {
        int idx = tid + r * 256;
        int x = idx >> 4, kyi = idx & 15;
        float ar = 0.f, ai = 0.f;
#pragma unroll
        for (int kxi = 0; kxi < 16; kxi++) {
            int f = kxi < 8 ? kxi : kxi + 48;
            float2 t = tw[(f * x) & 63];
            float2 v = yfs[kyi][kxi];
            ar += v.x * t.x - v.y * t.y;          // (vr+ivi)(c + i s)
            ai += v.x * t.y + v.y * t.x;
        }
        U1[base + idx] = make_float2(ar, ai);
    }
}

// inverse y: U2[b][kz][x][y][o] = sum_ky U1 * e^{+i}
__global__ __launch_bounds__(64) void k_yinv(const float2* __restrict__ U1,
                                             float2* __restrict__ U2) {
    int blk = blockIdx.x;                         // 2048 = (b,kz,x)
    int x = blk & 63, kz = (blk >> 6) & 7, b = blk >> 9;
    __shared__ float2 u1s[32][16];
    __shared__ float2 tw[64];
    int tid = threadIdx.x;                        // 64 (= y)
    { float s, c; sincosf(TW_STEP * tid, &s, &c); tw[tid] = make_float2(c, s); }
#pragma unroll
    for (int j = 0; j < 8; j++) {
        int idx = tid + j * 64;
        int o = idx >> 4, kyi = idx & 15;
        u1s[o][kyi] = U1[((b * 32 + o) * 8 + kz) * 1024 + x * 16 + kyi];
    }
    __syncthreads();
    int y = tid;
    float tc[16], ts[16];
#pragma unroll
    for (int ki = 0; ki < 16; ki++) {
        int f = ki < 8 ? ki : ki + 48;
        float2 t = tw[(f * y) & 63];
        tc[ki] = t.x; ts[ki] = t.y;
    }
    float2 acc[32];
#pragma unroll
    for (int o = 0; o < 32; o++) {
        float ar = 0.f, ai = 0.f;
#pragma unroll
        for (int ki = 0; ki < 16; ki++) {
            float2 v = u1s[o][ki];
            ar += v.x * tc[ki] - v.y * ts[ki];
            ai += v.x * ts[ki] + v.y * tc[ki];
        }
        acc[o] = make_float2(ar, ai);
    }
    float2* row = U2 + (size_t)(((b * 8 + kz) * 64 + x) * 64 + y) * 32;
    float4* r4 = (float4*)row;
#pragma unroll
    for (int j = 0; j < 16; j++)
        r4[j] = make_float4(acc[2 * j].x, acc[2 * j].y, acc[2 * j + 1].x, acc[2 * j + 1].y);
}

// fused: s = irfft_z(U2) + pointwise(h) + cb ; in-place overwrite of P.
// h = bn+relu transform of current P contents (same transform as k_zfwd used).
__global__ __launch_bounds__(256) void k_fuse(float* __restrict__ P,
                                              const float2* __restrict__ U2,
                                              const float* __restrict__ cwl,
                                              const float* __restrict__ cbl,
                                              const float* __restrict__ bnp, int relu) {
    int blk = blockIdx.x;                         // 4096 = (b,x,yt)
    int yt = blk & 15, x = (blk >> 4) & 63, b = blk >> 10;
    int y0 = yt * 4;
    __shared__ float hs[32][4][64];               // 32KB
    __shared__ float2 u2s[8][4][33];              // padded
    __shared__ float2 tw[64];
    int tid = threadIdx.x;
    if (tid < 64) { float s, c; sincosf(TW_STEP * tid, &s, &c); tw[tid] = make_float2(c, s); }
    int zl = tid & 63, yl = (tid >> 6) & 3;
    for (int c = 0; c < 32; c++) {
        float v = P[(size_t)(((b * 32 + c) * 64 + x) * 64 + (y0 + yl)) * 64 + zl];
        if (bnp) { v = v * bnp[c] + bnp[32 + c]; if (relu) v = fmaxf(v, 0.f); }
        hs[c][yl][zl] = v;
    }
#pragma unroll
    for (int j = 0; j < 4; j++) {
        int idx = tid + j * 256;                  // 1024
        int kz = idx >> 7, rem = idx & 127, yy = rem >> 5, o = rem & 31;
        u2s[kz][yy][o] = U2[(size_t)(((b * 8 + kz) * 64 + x) * 64 + (y0 + yy)) * 32 + o];
    }
    __syncthreads();
    float tc[8], ts[8];
#pragma unroll
    for (int k = 1; k < 8; k++) { float2 t = tw[(k * zl) & 63]; tc[k] = t.x; ts[k] = t.y; }
    float acc[32];
#pragma unroll
    for (int o = 0; o < 32; o++) acc[o] = cbl[o];
    for (int c = 0; c < 32; c++) {
        float hv = hs[c][yl][zl];
#pragma unroll
        for (int o = 0; o < 32; o++) acc[o] = fmaf(cwl[o * 32 + c], hv, acc[o]);
    }
#pragma unroll
    for (int o = 0; o < 32; o++) {
        float2 c0 = u2s[0][yl][o];
        float v = c0.x;                           // irfft drops Im of DC bin
#pragma unroll
        for (int k = 1; k < 8; k++) {
            float2 ck = u2s[k][yl][o];
            v += 2.f * (ck.x * tc[k] - ck.y * ts[k]);
        }
        acc[o] += v;
    }
#pragma unroll
    for (int o = 0; o < 32; o++)
        P[(size_t)(((b * 32 + o) * 64 + x) * 64 + (y0 + yl)) * 64 + zl] = acc[o];
}

// per-channel partial sums for batchnorm (deterministic two-stage)
__global__ __launch_bounds__(256) void k_stats(const float* __restrict__ P,
                                               float* __restrict__ part) {
    int blk = blockIdx.x;                         // 512 = ((b*32+c)*4+q)
    int q = blk & 3, c = (blk >> 2) & 31, b = blk >> 7;
    const float4* base = (const float4*)(P + (size_t)(b * 32 + c) * 262144 + q * 65536);
    int tid = threadIdx.x;
    float s = 0.f, ss = 0.f;
    for (int j = 0; j < 64; j++) {
        float4 v = base[tid + j * 256];
        s += v.x + v.y + v.z + v.w;
        ss += v.x * v.x + v.y * v.y + v.z * v.z + v.w * v.w;
    }
#pragma unroll
    for (int d = 32; d > 0; d >>= 1) {
        s += __shfl_down(s, d, 64);
        ss += __shfl_down(ss, d, 64);
    }
    __shared__ float wsum[4][2];
    int wave = tid >> 6;
    if ((tid & 63) == 0) { wsum[wave][0] = s; wsum[wave][1] = ss; }
    __syncthreads();
    if (tid == 0) {
        float S = wsum[0][0] + wsum[1][0] + wsum[2][0] + wsum[3][0];
        float SS = wsum[0][1] + wsum[1][1] + wsum[2][1] + wsum[3][1];
        int chunk = b * 4 + q;
        part[(c * 16 + chunk) * 2 + 0] = S;
        part[(c * 16 + chunk) * 2 + 1] = SS;
    }
}

__global__ void k_bnfin(const float* __restrict__ part, const float* __restrict__ gamma,
                        const float* __restrict__ beta, float* __restrict__ bnp) {
    int c = threadIdx.x;                          // 32
    if (c >= 32) return;
    double s = 0.0, ss = 0.0;
    for (int j = 0; j < 16; j++) { s += part[(c * 16 + j) * 2]; ss += part[(c * 16 + j) * 2 + 1]; }
    const double invN = 1.0 / 1048576.0;
    double mean = s * invN;
    double var = ss * invN - mean * mean;
    float scl = gamma[c] * rsqrtf((float)var + 1e-5f);
    bnp[c] = scl;
    bnp[32 + c] = beta[c] - (float)mean * scl;
}

// head: bn (no relu) -> fc1 + relu -> fc2
__global__ __launch_bounds__(256) void k_head(const float* __restrict__ P,
                                              const float* __restrict__ bnp,
                                              const float* __restrict__ w1,
                                              const float* __restrict__ b1,
                                              const float* __restrict__ w2,
                                              const float* __restrict__ b2,
                                              float* __restrict__ out) {
    int v = blockIdx.x * 256 + threadIdx.x;       // 1048576
    int z = v & 63, y = (v >> 6) & 63, x = (v >> 12) & 63, b = v >> 18;
    float h[32];
#pragma unroll
    for (int c = 0; c < 32; c++) {
        float val = P[(size_t)(((b * 32 + c) * 64 + x) * 64 + y) * 64 + z];
        h[c] = val * bnp[c] + bnp[32 + c];
    }
    float o = b2[0];
    for (int f = 0; f < 128; f++) {
        float a = b1[f];
#pragma unroll
        for (int w = 0; w < 32; w++) a = fmaf(w1[f * 32 + w], h[w], a);
        a = fmaxf(a, 0.f);
        o = fmaf(w2[f], a, o);
    }
    out[v] = o;
}

// ---------------- launcher ----------------
extern "C" void kernel_launch(void* const* d_in, const int* in_sizes, int n_in,
                              void* d_out, int out_size, void* d_ws, size_t ws_size,
                              hipStream_t stream) {
    const float* x     = (const float*)d_in[0];
    const float* fc0_w = (const float*)d_in[1];
    const float* fc0_b = (const float*)d_in[2];
    const float* sw    = (const float*)d_in[3];
    const float* cw    = (const float*)d_in[4];
    const float* cb    = (const float*)d_in[5];
    const float* gamma = (const float*)d_in[6];
    const float* beta  = (const float*)d_in[7];
    const float* fc1_w = (const float*)d_in[8];
    const float* fc1_b = (const float*)d_in[9];
    const float* fc2_w = (const float*)d_in[10];
    const float* fc2_b = (const float*)d_in[11];

    char* ws = (char*)d_ws;
    float*  P   = (float*)(ws + OFF_P);
    float2* A   = (float2*)(ws + OFF_A);    // T1 / U2
    float2* Bb  = (float2*)(ws + OFF_B2);   // T2 / U1
    float2* Xf  = (float2*)(ws + OFF_XF);
    float2* Yf  = (float2*)(ws + OFF_YF);
    float*  part = (float*)(ws + OFF_PART);
    float2* gtw = (float2*)(ws + OFF_TW);
    float*  bnp = (float*)(ws + OFF_BNP);   // [4][64]

    k_twinit<<<1, 64, 0, stream>>>(gtw);
    k_lift<<<4096, 256, 0, stream>>>(x, fc0_w, fc0_b, P);

    for (int i = 0; i < 4; i++) {
        const float* bprev = (i == 0) ? nullptr : (bnp + (i - 1) * 64);
        int relu = (i > 0) ? 1 : 0;
        k_zfwd<<<2048, 256, 0, stream>>>(P, gtw, bprev, relu, A);
        k_dftf<<<256, 256, 0, stream>>>(A, Bb, gtw, 65536, 0);
        k_dftf<<<64, 256, 0, stream>>>(Bb, Xf, gtw, 16384, 1);
        k_specmul<<<2048, 128, 0, stream>>>(Xf, sw + (size_t)i * 4194304, Yf);
        k_xinv<<<1024, 256, 0, stream>>>(Yf, Bb);
        k_yinv<<<2048, 64, 0, stream>>>(Bb, A);
        k_fuse<<<4096, 256, 0, stream>>>(P, A, cw + i * 1024, cb + i * 32, bprev, relu);
        k_stats<<<512, 256, 0, stream>>>(P, part);
        k_bnfin<<<1, 32, 0, stream>>>(part, gamma + i * 32, beta + i * 32, bnp + i * 64);
    }

    k_head<<<4096, 256, 0, stream>>>(P, bnp + 3 * 64, fc1_w, fc1_b, fc2_w, fc2_b, (float*)d_out);
}

// Round 2
// 1085.419 us; speedup vs baseline: 1.2185x; 1.2185x over previous
//
#include <hip/hip_runtime.h>

#define TW_STEP 0.09817477042468103f  // 2*pi/64

typedef __bf16 bf16x8 __attribute__((ext_vector_type(8)));
typedef float  f32x4  __attribute__((ext_vector_type(4)));

// ---------------- workspace layout (bytes) ----------------
static constexpr size_t SZ_P   = (size_t)4*32*64*64*64*4;   // 134217728  field P [B][C][X][Y][Z] fp32
static constexpr size_t SZ_A   = (size_t)4*32*8*64*64*8;    // 33554432   T1 [b][c][kz][x][y] f2  /  U2 [b][kz][x][y][o] f2
static constexpr size_t SZ_B2  = (size_t)4*32*8*16*64*8;    // 8388608    T2 / U1
static constexpr size_t SZ_XF  = (size_t)4*32*8*16*16*8;    // 2097152    Xf (also reused for bn partials)
static constexpr size_t OFF_P  = 0;
static constexpr size_t OFF_A  = OFF_P + SZ_P;
static constexpr size_t OFF_B2 = OFF_A + SZ_A;
static constexpr size_t OFF_XF = OFF_B2 + SZ_B2;
static constexpr size_t OFF_YF = OFF_XF + SZ_XF;
static constexpr size_t OFF_TW  = OFF_YF + SZ_XF;           // 64 float2
static constexpr size_t OFF_BNP = OFF_TW + 512;             // 4 layers * 64 floats
static constexpr size_t OFF_P2  = OFF_BNP + 1024;           // 128 floats

// ---------------- kernels ----------------

__global__ void k_twinit(float2* tw) {
    int t = threadIdx.x;
    if (t < 64) { float s, c; sincosf(TW_STEP * t, &s, &c); tw[t] = make_float2(c, s); }
}

// lift: x[B,X,Y,Z,3] -> P[b][w][x][y][z]
__global__ __launch_bounds__(256) void k_lift(const float* __restrict__ x,
                                              const float* __restrict__ w,
                                              const float* __restrict__ bias,
                                              float* __restrict__ P) {
    int v = blockIdx.x * 256 + threadIdx.x;      // 1048576 voxels
    int z = v & 63, y = (v >> 6) & 63, xx = (v >> 12) & 63, b = v >> 18;
    float i0 = x[(size_t)v * 3 + 0], i1 = x[(size_t)v * 3 + 1], i2 = x[(size_t)v * 3 + 2];
#pragma unroll
    for (int c = 0; c < 32; c++) {
        float val = bias[c] + w[c * 3 + 0] * i0 + w[c * 3 + 1] * i1 + w[c * 3 + 2] * i2;
        P[(size_t)(((b * 32 + c) * 64 + xx) * 64 + y) * 64 + z] = val;
    }
}

// forward z-DFT via Goertzel: P (with on-the-fly bn+relu) -> T1[b][c][kz][x][y]
__global__ __launch_bounds__(256) void k_zfwd(const float* __restrict__ P,
                                              const float2* __restrict__ gtw,
                                              const float* __restrict__ bnp, int relu,
                                              float2* __restrict__ T1) {
    int g = blockIdx.x * 256 + threadIdx.x;      // 524288 = (b,c,x,y)
    int y = g & 63, x = (g >> 6) & 63, c = (g >> 12) & 31, b = g >> 17;
    float sc = 1.f, sh = 0.f;
    if (bnp) { sc = bnp[c]; sh = bnp[32 + c]; }
    const float* row = P + (size_t)(((b * 32 + c) * 64 + x) * 64 + y) * 64;
    float ck[8], sk[8], c2[8];
#pragma unroll
    for (int k = 1; k < 8; k++) { float2 t = gtw[k]; ck[k] = t.x; sk[k] = t.y; c2[k] = 2.f * t.x; }
    float k0 = 0.f;
    float s1[8], s2[8];
#pragma unroll
    for (int k = 1; k < 8; k++) { s1[k] = 0.f; s2[k] = 0.f; }
#pragma unroll
    for (int q = 0; q < 16; q++) {
        float4 v4 = ((const float4*)row)[q];
        float vv[4] = {v4.x, v4.y, v4.z, v4.w};
#pragma unroll
        for (int j = 0; j < 4; j++) {
            float v = vv[j] * sc + sh;
            if (relu) v = fmaxf(v, 0.f);
            k0 += v;
#pragma unroll
            for (int k = 1; k < 8; k++) {
                float s0 = fmaf(c2[k], s1[k], v - s2[k]);
                s2[k] = s1[k]; s1[k] = s0;
            }
        }
    }
    int ob = ((b * 32 + c) * 8) * 4096 + x * 64 + y;
    T1[ob] = make_float2(k0, 0.f);
    // X_k = e^{i theta} S63 - S62  (theta = 2 pi k/64): Re = c*S63 - S62, Im = s*S63
#pragma unroll
    for (int k = 1; k < 8; k++)
        T1[ob + k * 4096] = make_float2(ck[k] * s1[k] - s2[k], sk[k] * s1[k]);
}

// forward 64->16 complex DFT along contiguous rows; 16 rows x 16 freqs per block.
// mode 0 (y-stage): rows t=(b,c,kz,x); out[(t>>6)*1024 + ki*64 + (t&63)]
// mode 1 (x-stage): rows t=(b,c,kz,kyi); out[t*16 + ki]
__global__ __launch_bounds__(256) void k_dft2(const float2* __restrict__ in,
                                              float2* __restrict__ out,
                                              const float2* __restrict__ gtw,
                                              int mode) {
    int rb = blockIdx.x * 16;
    __shared__ float2 rows[16][65];
    int tid = threadIdx.x;
#pragma unroll
    for (int k = 0; k < 4; k++) {
        int idx = tid + k * 256;
        int r = idx >> 6, y = idx & 63;
        rows[r][y] = in[(size_t)(rb + r) * 64 + y];
    }
    __syncthreads();
    int ki = tid & 15, r = tid >> 4;
    int f = ki < 8 ? ki : ki + 48;
    float2 w = gtw[f];                            // (cos, sin) of +f*step
    float tc = 1.f, ts = 0.f;                     // e^{-i f theta y}
    float ar = 0.f, ai = 0.f;
#pragma unroll 8
    for (int y = 0; y < 64; y++) {
        float2 v = rows[r][y];
        ar = fmaf(v.x, tc, ar); ar = fmaf(-v.y, ts, ar);
        ai = fmaf(v.x, ts, ai); ai = fmaf(v.y, tc, ai);
        float nc = fmaf(tc, w.x, ts * w.y);
        float ns = fmaf(ts, w.x, -tc * w.y);
        tc = nc; ts = ns;
    }
    int rg = rb + r;
    if (mode == 0) out[(rg >> 6) * 1024 + ki * 64 + (rg & 63)] = make_float2(ar, ai);
    else           out[rg * 16 + ki] = make_float2(ar, ai);
}

// spectral multiply: Yf[b][o][m] = (1/64^3) * sum_i Xf[b][i][m] * w[corner][i][o][modes]
__global__ __launch_bounds__(128) void k_specmul(const float2* __restrict__ Xf,
                                                 const float* __restrict__ swl,
                                                 float2* __restrict__ Yf) {
    int m = blockIdx.x;                           // 2048 = (kz,kyi,kxi)
    int kxi = m & 15, kyi = (m >> 4) & 15, kz = m >> 8;
    int corner = (kxi >= 8 ? 1 : 0) + (kyi >= 8 ? 2 : 0);
    int mx = kxi & 7, my = kyi & 7;
    __shared__ float2 wsd[1024];
    __shared__ float2 xfs[128];
    int tid = threadIdx.x;
    const float* wb = swl + (size_t)corner * 1048576 + mx * 128 + my * 16 + kz * 2;
    for (int idx = tid; idx < 1024; idx += 128) {
        int i = idx >> 5, o = idx & 31;
        const float* p = wb + (size_t)i * 32768 + o * 1024;
        wsd[idx] = make_float2(p[0], p[1]);
    }
    {
        int b = tid >> 5, i = tid & 31;
        xfs[tid] = Xf[(((b * 32 + i) * 8 + kz) * 16 + kyi) * 16 + kxi];
    }
    __syncthreads();
    int b = tid >> 5, o = tid & 31;
    float ar = 0.f, ai = 0.f;
#pragma unroll
    for (int i = 0; i < 32; i++) {
        float2 xv = xfs[b * 32 + i];
        float2 wv = wsd[i * 32 + o];
        ar += xv.x * wv.x - xv.y * wv.y;
        ai += xv.x * wv.y + xv.y * wv.x;
    }
    const float s = 1.0f / 262144.0f;
    Yf[(((b * 32 + o) * 8 + kz) * 16 + kyi) * 16 + kxi] = make_float2(ar * s, ai * s);
}

// inverse x: U1[b][o][kz][x][kyi] = sum_kx Yf * e^{+i}
__global__ __launch_bounds__(256) void k_xinv(const float2* __restrict__ Yf,
                                              float2* __restrict__ U1) {
    int blk = blockIdx.x;                         // 1024 = (b,o,kz)
    int kz = blk & 7, o = (blk >> 3) & 31, b = blk >> 8;
    __shared__ float2 yfs[16][17];
    __shared__ float2 tw[64];
    int tid = threadIdx.x;
    if (tid < 64) { float s, c; sincosf(TW_STEP * tid, &s, &c); tw[tid] = make_float2(c, s); }
    {
        int kyi = tid >> 4, kxi = tid & 15;
        yfs[kyi][kxi] = Yf[(size_t)((b * 32 + o) * 8 + kz) * 256 + tid];
    }
    __syncthreads();
    int base = ((b * 32 + o) * 8 + kz) * 1024;
#pragma unroll
    for (int r = 0; r < 4; r++) {
        int idx = tid + r * 256;
        int x = idx >> 4, kyi = idx & 15;
        float ar = 0.f, ai = 0.f;
#pragma unroll
        for (int kxi = 0; kxi < 16; kxi++) {
            int f = kxi < 8 ? kxi : kxi + 48;
            float2 t = tw[(f * x) & 63];
            float2 v = yfs[kyi][kxi];
            ar += v.x * t.x - v.y * t.y;
            ai += v.x * t.y + v.y * t.x;
        }
        U1[base + idx] = make_float2(ar, ai);
    }
}

// inverse y: U2[b][kz][x][y][o] = sum_ky U1 * e^{+i}
__global__ __launch_bounds__(64) void k_yinv(const float2* __restrict__ U1,
                                             float2* __restrict__ U2) {
    int blk = blockIdx.x;                         // 2048 = (b,kz,x)
    int x = blk & 63, kz = (blk >> 6) & 7, b = blk >> 9;
    __shared__ float2 u1s[32][16];
    __shared__ float2 tw[64];
    int tid = threadIdx.x;                        // 64 (= y)
    { float s, c; sincosf(TW_STEP * tid, &s, &c); tw[tid] = make_float2(c, s); }
#pragma unroll
    for (int j = 0; j < 8; j++) {
        int idx = tid + j * 64;
        int o = idx >> 4, kyi = idx & 15;
        u1s[o][kyi] = U1[((b * 32 + o) * 8 + kz) * 1024 + x * 16 + kyi];
    }
    __syncthreads();
    int y = tid;
    float tc[16], ts[16];
#pragma unroll
    for (int ki = 0; ki < 16; ki++) {
        int f = ki < 8 ? ki : ki + 48;
        float2 t = tw[(f * y) & 63];
        tc[ki] = t.x; ts[ki] = t.y;
    }
    float2 acc[32];
#pragma unroll
    for (int o = 0; o < 32; o++) {
        float ar = 0.f, ai = 0.f;
#pragma unroll
        for (int ki = 0; ki < 16; ki++) {
            float2 v = u1s[o][ki];
            ar += v.x * tc[ki] - v.y * ts[ki];
            ai += v.x * ts[ki] + v.y * tc[ki];
        }
        acc[o] = make_float2(ar, ai);
    }
    float2* rowp = U2 + (size_t)(((b * 8 + kz) * 64 + x) * 64 + y) * 32;
    float4* r4 = (float4*)rowp;
#pragma unroll
    for (int j = 0; j < 16; j++)
        r4[j] = make_float4(acc[2 * j].x, acc[2 * j].y, acc[2 * j + 1].x, acc[2 * j + 1].y);
}

// fused: s = irfft_z(U2) + pointwise(h) + cb ; in-place overwrite of P; emits bn partial sums.
__global__ __launch_bounds__(256) void k_fuse(float* __restrict__ P,
                                              const float2* __restrict__ U2,
                                              const float* __restrict__ cwl,
                                              const float* __restrict__ cbl,
                                              const float* __restrict__ bnp, int relu,
                                              float* __restrict__ part) {
    int blk = blockIdx.x;                         // 4096 = (b,x,yt)
    int yt = blk & 15, x = (blk >> 4) & 63, b = blk >> 10;
    int y0 = yt * 4;
    __shared__ float smem[10432];                 // hs[32][4][64] | u2s 8*4*33 f2 | tw 64 f2
    float  (*hs)[4][64] = (float(*)[4][64])smem;
    float2 (*u2s)[4][33] = (float2(*)[4][33])(smem + 8192);
    float2* twp = (float2*)(smem + 8192 + 2112);
    int tid = threadIdx.x;
    if (tid < 64) { float s, c; sincosf(TW_STEP * tid, &s, &c); twp[tid] = make_float2(c, s); }
    int zl = tid & 63, yl = (tid >> 6) & 3;
    for (int c = 0; c < 32; c++) {
        float v = P[(size_t)(((b * 32 + c) * 64 + x) * 64 + (y0 + yl)) * 64 + zl];
        if (bnp) { v = v * bnp[c] + bnp[32 + c]; if (relu) v = fmaxf(v, 0.f); }
        hs[c][yl][zl] = v;
    }
#pragma unroll
    for (int j = 0; j < 4; j++) {
        int idx = tid + j * 256;                  // 1024
        int kz = idx >> 7, rem = idx & 127, yy = rem >> 5, o = rem & 31;
        u2s[kz][yy][o] = U2[(size_t)(((b * 8 + kz) * 64 + x) * 64 + (y0 + yy)) * 32 + o];
    }
    __syncthreads();
    float tc[8], ts[8];
#pragma unroll
    for (int k = 1; k < 8; k++) { float2 t = twp[(k * zl) & 63]; tc[k] = t.x; ts[k] = t.y; }
    float acc[32];
#pragma unroll
    for (int o = 0; o < 32; o++) acc[o] = cbl[o];
    for (int c = 0; c < 32; c++) {
        float hv = hs[c][yl][zl];
#pragma unroll
        for (int o = 0; o < 32; o++) acc[o] = fmaf(cwl[o * 32 + c], hv, acc[o]);
    }
#pragma unroll
    for (int o = 0; o < 32; o++) {
        float2 c0 = u2s[0][yl][o];
        float v = c0.x;                           // irfft drops Im of DC bin
#pragma unroll
        for (int k = 1; k < 8; k++) {
            float2 ckk = u2s[k][yl][o];
            v += 2.f * (ckk.x * tc[k] - ckk.y * ts[k]);
        }
        acc[o] += v;
    }
#pragma unroll
    for (int o = 0; o < 32; o++)
        P[(size_t)(((b * 32 + o) * 64 + x) * 64 + (y0 + yl)) * 64 + zl] = acc[o];

    // ---- bn partial sums over this block's 256 voxels ----
    __syncthreads();                               // hs/u2s dead now
#pragma unroll
    for (int o = 0; o < 32; o++) smem[o * 258 + tid] = acc[o];
    __syncthreads();
    {
        int oo = tid & 31, seg = tid >> 5;
        float s = 0.f, ss = 0.f;
#pragma unroll
        for (int j = 0; j < 32; j++) {
            float v = smem[oo * 258 + seg * 32 + j];
            s += v; ss = fmaf(v, v, ss);
        }
        float* red2 = smem + 8256;
        red2[(oo * 8 + seg) * 2 + 0] = s;
        red2[(oo * 8 + seg) * 2 + 1] = ss;
        __syncthreads();
        if (tid < 32) {
            float S = 0.f, SS = 0.f;
#pragma unroll
            for (int q = 0; q < 8; q++) { S += red2[(tid * 8 + q) * 2]; SS += red2[(tid * 8 + q) * 2 + 1]; }
            part[((size_t)tid * 4096 + blk) * 2 + 0] = S;
            part[((size_t)tid * 4096 + blk) * 2 + 1] = SS;
        }
    }
}

// reduce 4096 block-partials -> 2 halves per channel
__global__ __launch_bounds__(256) void k_red(const float* __restrict__ part,
                                             float* __restrict__ part2) {
    int o = blockIdx.x >> 1, h = blockIdx.x & 1;
    int tid = threadIdx.x;
    int base = o * 4096 + h * 2048 + tid * 8;
    float s = 0.f, ss = 0.f;
#pragma unroll
    for (int q = 0; q < 8; q++) { s += part[(size_t)(base + q) * 2]; ss += part[(size_t)(base + q) * 2 + 1]; }
#pragma unroll
    for (int d = 32; d; d >>= 1) { s += __shfl_down(s, d, 64); ss += __shfl_down(ss, d, 64); }
    __shared__ float w4[8];
    if ((tid & 63) == 0) { w4[(tid >> 6) * 2] = s; w4[(tid >> 6) * 2 + 1] = ss; }
    __syncthreads();
    if (tid == 0) {
        part2[blockIdx.x * 2 + 0] = w4[0] + w4[2] + w4[4] + w4[6];
        part2[blockIdx.x * 2 + 1] = w4[1] + w4[3] + w4[5] + w4[7];
    }
}

__global__ void k_bnfin(const float* __restrict__ part2, const float* __restrict__ gamma,
                        const float* __restrict__ beta, float* __restrict__ bnp) {
    int c = threadIdx.x;                          // 32
    if (c >= 32) return;
    double s = (double)part2[c * 4] + (double)part2[c * 4 + 2];
    double ss = (double)part2[c * 4 + 1] + (double)part2[c * 4 + 3];
    const double invN = 1.0 / 1048576.0;
    double mean = s * invN;
    double var = ss * invN - mean * mean;
    float scl = gamma[c] * rsqrtf((float)var + 1e-5f);
    bnp[c] = scl;
    bnp[32 + c] = beta[c] - (float)mean * scl;
}

// head: bn (no relu) -> fc1(MFMA bf16) + relu -> fc2
__global__ __launch_bounds__(256) void k_head(const float* __restrict__ P,
                                              const float* __restrict__ bnp,
                                              const float* __restrict__ w1,
                                              const float* __restrict__ b1,
                                              const float* __restrict__ w2,
                                              const float* __restrict__ b2,
                                              float* __restrict__ out) {
    __shared__ __bf16 hs[64 * 40];                // [vox][ch], stride 40 (80B, 16B-aligned)
    int tid = threadIdx.x;
    int b = blockIdx.x >> 12;                     // 4096 blocks per batch (64 vox each)
    int r0 = (blockIdx.x & 4095) * 64;            // within-batch voxel offset (z-y-x linear)
    int l = tid & 63;

    // B fragments: w1[f][k], f = nt*16 + (l&15), k = (l>>4)*8 + j
    bf16x8 bfr[8];
    {
        int col = l & 15, kg = l >> 4;
        const float4* w1v = (const float4*)w1;
#pragma unroll
        for (int nt = 0; nt < 8; nt++) {
            int f = nt * 16 + col;
            float4 q0 = w1v[f * 8 + kg * 2];
            float4 q1 = w1v[f * 8 + kg * 2 + 1];
            bfr[nt][0] = (__bf16)q0.x; bfr[nt][1] = (__bf16)q0.y;
            bfr[nt][2] = (__bf16)q0.z; bfr[nt][3] = (__bf16)q0.w;
            bfr[nt][4] = (__bf16)q1.x; bfr[nt][5] = (__bf16)q1.y;
            bfr[nt][6] = (__bf16)q1.z; bfr[nt][7] = (__bf16)q1.w;
        }
    }
    // stage h tile: thread (c = tid&31, j = tid>>5) loads 8 voxels of channel c
    {
        int c = tid & 31, j = tid >> 5;
        const float* src = P + (size_t)(b * 32 + c) * 262144 + r0 + j * 8;
        float4 v0 = ((const float4*)src)[0];
        float4 v1 = ((const float4*)src)[1];
        float sc = bnp[c], sh = bnp[32 + c];
        float vals[8] = {v0.x, v0.y, v0.z, v0.w, v1.x, v1.y, v1.z, v1.w};
#pragma unroll
        for (int jj = 0; jj < 8; jj++)
            hs[(j * 8 + jj) * 40 + c] = (__bf16)(vals[jj] * sc + sh);
    }
    __syncthreads();

    int w = tid >> 6;                             // wave id: voxels w*16..w*16+15
    int row = l & 15, kg = l >> 4;
    bf16x8 a = *(const bf16x8*)&hs[(w * 16 + row) * 40 + kg * 8];
    f32x4 acc[8];
#pragma unroll
    for (int nt = 0; nt < 8; nt++) {
        acc[nt] = (f32x4){0.f, 0.f, 0.f, 0.f};
        acc[nt] = __builtin_amdgcn_mfma_f32_16x16x32_bf16(a, bfr[nt], acc[nt], 0, 0, 0);
    }
    // epilogue: relu(fc1 + b1) dot w2, reduce across the 16 col-lanes
    float s[4] = {0.f, 0.f, 0.f, 0.f};
#pragma unroll
    for (int nt = 0; nt < 8; nt++) {
        int f = nt * 16 + (l & 15);
        float b1v = b1[f], w2v = w2[f];
#pragma unroll
        for (int r = 0; r < 4; r++) {
            float val = fmaxf(acc[nt][r] + b1v, 0.f);
            s[r] = fmaf(w2v, val, s[r]);
        }
    }
#pragma unroll
    for (int r = 0; r < 4; r++) {
        s[r] += __shfl_xor(s[r], 1, 64);
        s[r] += __shfl_xor(s[r], 2, 64);
        s[r] += __shfl_xor(s[r], 4, 64);
        s[r] += __shfl_xor(s[r], 8, 64);
    }
    if ((l & 15) == 0) {
        float b2v = b2[0];
        int vb = blockIdx.x * 64 + w * 16 + (l >> 4) * 4;
#pragma unroll
        for (int r = 0; r < 4; r++) out[vb + r] = s[r] + b2v;
    }
}

// ---------------- launcher ----------------
extern "C" void kernel_launch(void* const* d_in, const int* in_sizes, int n_in,
                              void* d_out, int out_size, void* d_ws, size_t ws_size,
                              hipStream_t stream) {
    const float* x     = (const float*)d_in[0];
    const float* fc0_w = (const float*)d_in[1];
    const float* fc0_b = (const float*)d_in[2];
    const float* sw    = (const float*)d_in[3];
    const float* cw    = (const float*)d_in[4];
    const float* cb    = (const float*)d_in[5];
    const float* gamma = (const float*)d_in[6];
    const float* beta  = (const float*)d_in[7];
    const float* fc1_w = (const float*)d_in[8];
    const float* fc1_b = (const float*)d_in[9];
    const float* fc2_w = (const float*)d_in[10];
    const float* fc2_b = (const float*)d_in[11];

    char* ws = (char*)d_ws;
    float*  P    = (float*)(ws + OFF_P);
    float2* A    = (float2*)(ws + OFF_A);   // T1 / U2
    float2* Bb   = (float2*)(ws + OFF_B2);  // T2 / U1
    float2* Xf   = (float2*)(ws + OFF_XF);
    float2* Yf   = (float2*)(ws + OFF_YF);
    float*  part = (float*)(ws + OFF_XF);   // reuse Xf region (dead during k_fuse..k_bnfin)
    float2* gtw  = (float2*)(ws + OFF_TW);
    float*  bnp  = (float*)(ws + OFF_BNP);  // [4][64]
    float*  p2   = (float*)(ws + OFF_P2);   // [32][2 halves][2]

    k_twinit<<<1, 64, 0, stream>>>(gtw);
    k_lift<<<4096, 256, 0, stream>>>(x, fc0_w, fc0_b, P);

    for (int i = 0; i < 4; i++) {
        const float* bprev = (i == 0) ? nullptr : (bnp + (i - 1) * 64);
        int relu = (i > 0) ? 1 : 0;
        k_zfwd<<<2048, 256, 0, stream>>>(P, gtw, bprev, relu, A);
        k_dft2<<<4096, 256, 0, stream>>>(A, Bb, gtw, 0);
        k_dft2<<<1024, 256, 0, stream>>>(Bb, Xf, gtw, 1);
        k_specmul<<<2048, 128, 0, stream>>>(Xf, sw + (size_t)i * 4194304, Yf);
        k_xinv<<<1024, 256, 0, stream>>>(Yf, Bb);
        k_yinv<<<2048, 64, 0, stream>>>(Bb, A);
        k_fuse<<<4096, 256, 0, stream>>>(P, A, cw + i * 1024, cb + i * 32, bprev, relu, part);
        k_red<<<64, 256, 0, stream>>>(part, p2);
        k_bnfin<<<1, 32, 0, stream>>>(p2, gamma + i * 32, beta + i * 32, bnp + i * 64);
    }

    k_head<<<16384, 256, 0, stream>>>(P, bnp + 3 * 64, fc1_w, fc1_b, fc2_w, fc2_b, (float*)d_out);
}

// Round 3
// 950.495 us; speedup vs baseline: 1.3915x; 1.1420x over previous
//
#include <hip/hip_runtime.h>

#define TW_STEP 0.09817477042468103f  // 2*pi/64

typedef __bf16 bf16x8 __attribute__((ext_vector_type(8)));
typedef float  f32x4  __attribute__((ext_vector_type(4)));

// ---------------- workspace layout (bytes) ----------------
static constexpr size_t SZ_P   = (size_t)4*32*64*64*64*2;   // 67108864  field P [B][C][X][Y][Z] bf16
static constexpr size_t SZ_A   = (size_t)4*32*8*64*64*8;    // 33554432  T1 [b][c][kz][x][y] f2 / U2 [b][kz][x][y][o] f2
static constexpr size_t SZ_B2  = (size_t)4*32*8*16*64*8;    // 8388608   T2 / U1
static constexpr size_t SZ_XF  = (size_t)4*32*8*16*16*8;    // 2097152   Xf (also reused for bn partials)
static constexpr size_t OFF_P  = 0;
static constexpr size_t OFF_A  = OFF_P + SZ_P;
static constexpr size_t OFF_B2 = OFF_A + SZ_A;
static constexpr size_t OFF_XF = OFF_B2 + SZ_B2;
static constexpr size_t OFF_YF = OFF_XF + SZ_XF;
static constexpr size_t OFF_TW  = OFF_YF + SZ_XF;           // 64 float2
static constexpr size_t OFF_BNP = OFF_TW + 512;             // 4 layers * 64 floats
static constexpr size_t OFF_P2  = OFF_BNP + 1024;           // 128 floats

// ---------------- kernels ----------------

__global__ void k_twinit(float2* tw) {
    int t = threadIdx.x;
    if (t < 64) { float s, c; sincosf(TW_STEP * t, &s, &c); tw[t] = make_float2(c, s); }
}

// lift: x[B,X,Y,Z,3] -> P[b][w][x][y][z] (bf16)
__global__ __launch_bounds__(256) void k_lift(const float* __restrict__ x,
                                              const float* __restrict__ w,
                                              const float* __restrict__ bias,
                                              __bf16* __restrict__ P) {
    int v = blockIdx.x * 256 + threadIdx.x;      // 1048576 voxels
    int z = v & 63, y = (v >> 6) & 63, xx = (v >> 12) & 63, b = v >> 18;
    float i0 = x[(size_t)v * 3 + 0], i1 = x[(size_t)v * 3 + 1], i2 = x[(size_t)v * 3 + 2];
#pragma unroll
    for (int c = 0; c < 32; c++) {
        float val = bias[c] + w[c * 3 + 0] * i0 + w[c * 3 + 1] * i1 + w[c * 3 + 2] * i2;
        P[(size_t)(((b * 32 + c) * 64 + xx) * 64 + y) * 64 + z] = (__bf16)val;
    }
}

// forward z-DFT via Goertzel: P (with on-the-fly bn+relu) -> T1[b][c][kz][x][y]
__global__ __launch_bounds__(256) void k_zfwd(const __bf16* __restrict__ P,
                                              const float2* __restrict__ gtw,
                                              const float* __restrict__ bnp, int relu,
                                              float2* __restrict__ T1) {
    int g = blockIdx.x * 256 + threadIdx.x;      // 524288 = (b,c,x,y)
    int y = g & 63, x = (g >> 6) & 63, c = (g >> 12) & 31, b = g >> 17;
    float sc = 1.f, sh = 0.f;
    if (bnp) { sc = bnp[c]; sh = bnp[32 + c]; }
    const __bf16* row = P + (size_t)(((b * 32 + c) * 64 + x) * 64 + y) * 64;
    float ck[8], sk[8], c2[8];
#pragma unroll
    for (int k = 1; k < 8; k++) { float2 t = gtw[k]; ck[k] = t.x; sk[k] = t.y; c2[k] = 2.f * t.x; }
    float k0 = 0.f;
    float s1[8], s2[8];
#pragma unroll
    for (int k = 1; k < 8; k++) { s1[k] = 0.f; s2[k] = 0.f; }
#pragma unroll
    for (int q = 0; q < 8; q++) {
        bf16x8 v8 = ((const bf16x8*)row)[q];
#pragma unroll
        for (int j = 0; j < 8; j++) {
            float v = (float)v8[j] * sc + sh;
            if (relu) v = fmaxf(v, 0.f);
            k0 += v;
#pragma unroll
            for (int k = 1; k < 8; k++) {
                float s0 = fmaf(c2[k], s1[k], v - s2[k]);
                s2[k] = s1[k]; s1[k] = s0;
            }
        }
    }
    int ob = ((b * 32 + c) * 8) * 4096 + x * 64 + y;
    T1[ob] = make_float2(k0, 0.f);
    // X_k = e^{i theta} S63 - S62: Re = c*S63 - S62, Im = s*S63
#pragma unroll
    for (int k = 1; k < 8; k++)
        T1[ob + k * 4096] = make_float2(ck[k] * s1[k] - s2[k], sk[k] * s1[k]);
}

// forward 64->16 complex DFT along contiguous rows; 16 rows x 16 freqs per block.
__global__ __launch_bounds__(256) void k_dft2(const float2* __restrict__ in,
                                              float2* __restrict__ out,
                                              const float2* __restrict__ gtw,
                                              int mode) {
    int rb = blockIdx.x * 16;
    __shared__ float2 rows[16][65];
    int tid = threadIdx.x;
#pragma unroll
    for (int k = 0; k < 4; k++) {
        int idx = tid + k * 256;
        int r = idx >> 6, y = idx & 63;
        rows[r][y] = in[(size_t)(rb + r) * 64 + y];
    }
    __syncthreads();
    int ki = tid & 15, r = tid >> 4;
    int f = ki < 8 ? ki : ki + 48;
    float2 w = gtw[f];                            // (cos, sin) of +f*step
    float tc = 1.f, ts = 0.f;                     // e^{-i f theta y}
    float ar = 0.f, ai = 0.f;
#pragma unroll 8
    for (int y = 0; y < 64; y++) {
        float2 v = rows[r][y];
        ar = fmaf(v.x, tc, ar); ar = fmaf(-v.y, ts, ar);
        ai = fmaf(v.x, ts, ai); ai = fmaf(v.y, tc, ai);
        float nc = fmaf(tc, w.x, ts * w.y);
        float ns = fmaf(ts, w.x, -tc * w.y);
        tc = nc; ts = ns;
    }
    int rg = rb + r;
    if (mode == 0) out[(rg >> 6) * 1024 + ki * 64 + (rg & 63)] = make_float2(ar, ai);
    else           out[rg * 16 + ki] = make_float2(ar, ai);
}

// spectral multiply
__global__ __launch_bounds__(128) void k_specmul(const float2* __restrict__ Xf,
                                                 const float* __restrict__ swl,
                                                 float2* __restrict__ Yf) {
    int m = blockIdx.x;                           // 2048 = (kz,kyi,kxi)
    int kxi = m & 15, kyi = (m >> 4) & 15, kz = m >> 8;
    int corner = (kxi >= 8 ? 1 : 0) + (kyi >= 8 ? 2 : 0);
    int mx = kxi & 7, my = kyi & 7;
    __shared__ float2 wsd[1024];
    __shared__ float2 xfs[128];
    int tid = threadIdx.x;
    const float* wb = swl + (size_t)corner * 1048576 + mx * 128 + my * 16 + kz * 2;
    for (int idx = tid; idx < 1024; idx += 128) {
        int i = idx >> 5, o = idx & 31;
        const float* p = wb + (size_t)i * 32768 + o * 1024;
        wsd[idx] = make_float2(p[0], p[1]);
    }
    {
        int b = tid >> 5, i = tid & 31;
        xfs[tid] = Xf[(((b * 32 + i) * 8 + kz) * 16 + kyi) * 16 + kxi];
    }
    __syncthreads();
    int b = tid >> 5, o = tid & 31;
    float ar = 0.f, ai = 0.f;
#pragma unroll
    for (int i = 0; i < 32; i++) {
        float2 xv = xfs[b * 32 + i];
        float2 wv = wsd[i * 32 + o];
        ar += xv.x * wv.x - xv.y * wv.y;
        ai += xv.x * wv.y + xv.y * wv.x;
    }
    const float s = 1.0f / 262144.0f;
    Yf[(((b * 32 + o) * 8 + kz) * 16 + kyi) * 16 + kxi] = make_float2(ar * s, ai * s);
}

// inverse x: U1[b][o][kz][x][kyi] = sum_kx Yf * e^{+i}
__global__ __launch_bounds__(256) void k_xinv(const float2* __restrict__ Yf,
                                              float2* __restrict__ U1) {
    int blk = blockIdx.x;                         // 1024 = (b,o,kz)
    int kz = blk & 7, o = (blk >> 3) & 31, b = blk >> 8;
    __shared__ float2 yfs[16][17];
    __shared__ float2 tw[64];
    int tid = threadIdx.x;
    if (tid < 64) { float s, c; sincosf(TW_STEP * tid, &s, &c); tw[tid] = make_float2(c, s); }
    {
        int kyi = tid >> 4, kxi = tid & 15;
        yfs[kyi][kxi] = Yf[(size_t)((b * 32 + o) * 8 + kz) * 256 + tid];
    }
    __syncthreads();
    int base = ((b * 32 + o) * 8 + kz) * 1024;
#pragma unroll
    for (int r = 0; r < 4; r++) {
        int idx = tid + r * 256;
        int x = idx >> 4, kyi = idx & 15;
        float ar = 0.f, ai = 0.f;
#pragma unroll
        for (int kxi = 0; kxi < 16; kxi++) {
            int f = kxi < 8 ? kxi : kxi + 48;
            float2 t = tw[(f * x) & 63];
            float2 v = yfs[kyi][kxi];
            ar += v.x * t.x - v.y * t.y;
            ai += v.x * t.y + v.y * t.x;
        }
        U1[base + idx] = make_float2(ar, ai);
    }
}

// inverse y: U2[b][kz][x][y][o] = sum_ky U1 * e^{+i}
__global__ __launch_bounds__(64) void k_yinv(const float2* __restrict__ U1,
                                             float2* __restrict__ U2) {
    int blk = blockIdx.x;                         // 2048 = (b,kz,x)
    int x = blk & 63, kz = (blk >> 6) & 7, b = blk >> 9;
    __shared__ float2 u1s[32][16];
    __shared__ float2 tw[64];
    int tid = threadIdx.x;                        // 64 (= y)
    { float s, c; sincosf(TW_STEP * tid, &s, &c); tw[tid] = make_float2(c, s); }
#pragma unroll
    for (int j = 0; j < 8; j++) {
        int idx = tid + j * 64;
        int o = idx >> 4, kyi = idx & 15;
        u1s[o][kyi] = U1[((b * 32 + o) * 8 + kz) * 1024 + x * 16 + kyi];
    }
    __syncthreads();
    int y = tid;
    float tc[16], ts[16];
#pragma unroll
    for (int ki = 0; ki < 16; ki++) {
        int f = ki < 8 ? ki : ki + 48;
        float2 t = tw[(f * y) & 63];
        tc[ki] = t.x; ts[ki] = t.y;
    }
    float2 acc[32];
#pragma unroll
    for (int o = 0; o < 32; o++) {
        float ar = 0.f, ai = 0.f;
#pragma unroll
        for (int ki = 0; ki < 16; ki++) {
            float2 v = u1s[o][ki];
            ar += v.x * tc[ki] - v.y * ts[ki];
            ai += v.x * ts[ki] + v.y * tc[ki];
        }
        acc[o] = make_float2(ar, ai);
    }
    float2* rowp = U2 + (size_t)(((b * 8 + kz) * 64 + x) * 64 + y) * 32;
    float4* r4 = (float4*)rowp;
#pragma unroll
    for (int j = 0; j < 16; j++)
        r4[j] = make_float4(acc[2 * j].x, acc[2 * j].y, acc[2 * j + 1].x, acc[2 * j + 1].y);
}

// fused: s = irfft_z(U2) + pointwise(h) + cb ; in-place overwrite of P; emits bn partial sums.
__global__ __launch_bounds__(256) void k_fuse(__bf16* __restrict__ P,
                                              const float2* __restrict__ U2,
                                              const float* __restrict__ cwl,
                                              const float* __restrict__ cbl,
                                              const float* __restrict__ bnp, int relu,
                                              float* __restrict__ part) {
    int blk = blockIdx.x;                         // 4096 = (b,x,yt)
    int yt = blk & 15, x = (blk >> 4) & 63, b = blk >> 10;
    int y0 = yt * 4;
    __shared__ float smem[10432];                 // hs[32][4][64] | u2s 8*4*33 f2 | tw 64 f2
    float  (*hs)[4][64] = (float(*)[4][64])smem;
    float2 (*u2s)[4][33] = (float2(*)[4][33])(smem + 8192);
    float2* twp = (float2*)(smem + 8192 + 2112);
    int tid = threadIdx.x;
    if (tid < 64) { float s, c; sincosf(TW_STEP * tid, &s, &c); twp[tid] = make_float2(c, s); }
    int zl = tid & 63, yl = (tid >> 6) & 3;
    for (int c = 0; c < 32; c++) {
        float v = (float)P[(size_t)(((b * 32 + c) * 64 + x) * 64 + (y0 + yl)) * 64 + zl];
        if (bnp) { v = v * bnp[c] + bnp[32 + c]; if (relu) v = fmaxf(v, 0.f); }
        hs[c][yl][zl] = v;
    }
#pragma unroll
    for (int j = 0; j < 4; j++) {
        int idx = tid + j * 256;                  // 1024
        int kz = idx >> 7, rem = idx & 127, yy = rem >> 5, o = rem & 31;
        u2s[kz][yy][o] = U2[(size_t)(((b * 8 + kz) * 64 + x) * 64 + (y0 + yy)) * 32 + o];
    }
    __syncthreads();
    float tc[8], ts[8];
#pragma unroll
    for (int k = 1; k < 8; k++) { float2 t = twp[(k * zl) & 63]; tc[k] = t.x; ts[k] = t.y; }
    float acc[32];
#pragma unroll
    for (int o = 0; o < 32; o++) acc[o] = cbl[o];
    for (int c = 0; c < 32; c++) {
        float hv = hs[c][yl][zl];
#pragma unroll
        for (int o = 0; o < 32; o++) acc[o] = fmaf(cwl[o * 32 + c], hv, acc[o]);
    }
#pragma unroll
    for (int o = 0; o < 32; o++) {
        float2 c0 = u2s[0][yl][o];
        float v = c0.x;                           // irfft drops Im of DC bin
#pragma unroll
        for (int k = 1; k < 8; k++) {
            float2 ckk = u2s[k][yl][o];
            v += 2.f * (ckk.x * tc[k] - ckk.y * ts[k]);
        }
        acc[o] += v;
    }
#pragma unroll
    for (int o = 0; o < 32; o++)
        P[(size_t)(((b * 32 + o) * 64 + x) * 64 + (y0 + yl)) * 64 + zl] = (__bf16)acc[o];

    // ---- bn partial sums over this block's 256 voxels (fp32 acc) ----
    __syncthreads();                               // hs/u2s dead now
#pragma unroll
    for (int o = 0; o < 32; o++) smem[o * 258 + tid] = acc[o];
    __syncthreads();
    {
        int oo = tid & 31, seg = tid >> 5;
        float s = 0.f, ss = 0.f;
#pragma unroll
        for (int j = 0; j < 32; j++) {
            float v = smem[oo * 258 + seg * 32 + j];
            s += v; ss = fmaf(v, v, ss);
        }
        float* red2 = smem + 8256;
        red2[(oo * 8 + seg) * 2 + 0] = s;
        red2[(oo * 8 + seg) * 2 + 1] = ss;
        __syncthreads();
        if (tid < 32) {
            float S = 0.f, SS = 0.f;
#pragma unroll
            for (int q = 0; q < 8; q++) { S += red2[(tid * 8 + q) * 2]; SS += red2[(tid * 8 + q) * 2 + 1]; }
            part[((size_t)tid * 4096 + blk) * 2 + 0] = S;
            part[((size_t)tid * 4096 + blk) * 2 + 1] = SS;
        }
    }
}

// reduce 4096 block-partials -> 2 halves per channel
__global__ __launch_bounds__(256) void k_red(const float* __restrict__ part,
                                             float* __restrict__ part2) {
    int o = blockIdx.x >> 1, h = blockIdx.x & 1;
    int tid = threadIdx.x;
    int base = o * 4096 + h * 2048 + tid * 8;
    float s = 0.f, ss = 0.f;
#pragma unroll
    for (int q = 0; q < 8; q++) { s += part[(size_t)(base + q) * 2]; ss += part[(size_t)(base + q) * 2 + 1]; }
#pragma unroll
    for (int d = 32; d; d >>= 1) { s += __shfl_down(s, d, 64); ss += __shfl_down(ss, d, 64); }
    __shared__ float w4[8];
    if ((tid & 63) == 0) { w4[(tid >> 6) * 2] = s; w4[(tid >> 6) * 2 + 1] = ss; }
    __syncthreads();
    if (tid == 0) {
        part2[blockIdx.x * 2 + 0] = w4[0] + w4[2] + w4[4] + w4[6];
        part2[blockIdx.x * 2 + 1] = w4[1] + w4[3] + w4[5] + w4[7];
    }
}

__global__ void k_bnfin(const float* __restrict__ part2, const float* __restrict__ gamma,
                        const float* __restrict__ beta, float* __restrict__ bnp) {
    int c = threadIdx.x;                          // 32
    if (c >= 32) return;
    double s = (double)part2[c * 4] + (double)part2[c * 4 + 2];
    double ss = (double)part2[c * 4 + 1] + (double)part2[c * 4 + 3];
    const double invN = 1.0 / 1048576.0;
    double mean = s * invN;
    double var = ss * invN - mean * mean;
    float scl = gamma[c] * rsqrtf((float)var + 1e-5f);
    bnp[c] = scl;
    bnp[32 + c] = beta[c] - (float)mean * scl;
}

// head: bn (no relu) -> fc1(MFMA bf16) + relu -> fc2. Persistent per-block weights,
// 8 tiles of 64 voxels per block (2048 blocks).
__global__ __launch_bounds__(256) void k_head(const __bf16* __restrict__ P,
                                              const float* __restrict__ bnp,
                                              const float* __restrict__ w1,
                                              const float* __restrict__ b1,
                                              const float* __restrict__ w2,
                                              const float* __restrict__ b2,
                                              float* __restrict__ out) {
    __shared__ __bf16 hs[64 * 40];                // [vox][ch], stride 40 (80B, 16B-aligned)
    int tid = threadIdx.x;
    int b = blockIdx.x >> 9;                      // 512 blocks per batch
    int r0 = (blockIdx.x & 511) * 512;            // 512 voxels per block
    int l = tid & 63;
    int w = tid >> 6;                             // wave id
    int col = l & 15, kg = l >> 4;

    // B fragments: w1[f][k], f = nt*16 + col, k = kg*8 + j  (loaded ONCE per block)
    bf16x8 bfr[8];
    float b1v[8], w2v[8];
    {
        const float4* w1v = (const float4*)w1;
#pragma unroll
        for (int nt = 0; nt < 8; nt++) {
            int f = nt * 16 + col;
            float4 q0 = w1v[f * 8 + kg * 2];
            float4 q1 = w1v[f * 8 + kg * 2 + 1];
            bfr[nt][0] = (__bf16)q0.x; bfr[nt][1] = (__bf16)q0.y;
            bfr[nt][2] = (__bf16)q0.z; bfr[nt][3] = (__bf16)q0.w;
            bfr[nt][4] = (__bf16)q1.x; bfr[nt][5] = (__bf16)q1.y;
            bfr[nt][6] = (__bf16)q1.z; bfr[nt][7] = (__bf16)q1.w;
            b1v[nt] = b1[f]; w2v[nt] = w2[f];
        }
    }
    float b2v = b2[0];
    int sc_c = tid & 31, sc_j = tid >> 5;
    float scb = bnp[sc_c], shb = bnp[32 + sc_c];
    const __bf16* srcb = P + (size_t)(b * 32 + sc_c) * 262144 + r0 + sc_j * 8;

    for (int t = 0; t < 8; t++) {
        // stage tile t: 64 voxels x 32 ch (thread (c,j) loads 8 voxels of channel c)
        {
            bf16x8 v8 = *(const bf16x8*)(srcb + t * 64);
#pragma unroll
            for (int jj = 0; jj < 8; jj++)
                hs[(sc_j * 8 + jj) * 40 + sc_c] = (__bf16)((float)v8[jj] * scb + shb);
        }
        __syncthreads();
        bf16x8 a = *(const bf16x8*)&hs[(w * 16 + (l & 15)) * 40 + kg * 8];
        f32x4 acc[8];
#pragma unroll
        for (int nt = 0; nt < 8; nt++) {
            acc[nt] = (f32x4){0.f, 0.f, 0.f, 0.f};
            acc[nt] = __builtin_amdgcn_mfma_f32_16x16x32_bf16(a, bfr[nt], acc[nt], 0, 0, 0);
        }
        float s[4] = {0.f, 0.f, 0.f, 0.f};
#pragma unroll
        for (int nt = 0; nt < 8; nt++) {
#pragma unroll
            for (int r = 0; r < 4; r++) {
                float val = fmaxf(acc[nt][r] + b1v[nt], 0.f);
                s[r] = fmaf(w2v[nt], val, s[r]);
            }
        }
#pragma unroll
        for (int r = 0; r < 4; r++) {
            s[r] += __shfl_xor(s[r], 1, 64);
            s[r] += __shfl_xor(s[r], 2, 64);
            s[r] += __shfl_xor(s[r], 4, 64);
            s[r] += __shfl_xor(s[r], 8, 64);
        }
        if ((l & 15) == 0) {
            int vb = b * 262144 + r0 + t * 64 + w * 16 + (l >> 4) * 4;
#pragma unroll
            for (int r = 0; r < 4; r++) out[vb + r] = s[r] + b2v;
        }
        __syncthreads();
    }
}

// ---------------- launcher ----------------
extern "C" void kernel_launch(void* const* d_in, const int* in_sizes, int n_in,
                              void* d_out, int out_size, void* d_ws, size_t ws_size,
                              hipStream_t stream) {
    const float* x     = (const float*)d_in[0];
    const float* fc0_w = (const float*)d_in[1];
    const float* fc0_b = (const float*)d_in[2];
    const float* sw    = (const float*)d_in[3];
    const float* cw    = (const float*)d_in[4];
    const float* cb    = (const float*)d_in[5];
    const float* gamma = (const float*)d_in[6];
    const float* beta  = (const float*)d_in[7];
    const float* fc1_w = (const float*)d_in[8];
    const float* fc1_b = (const float*)d_in[9];
    const float* fc2_w = (const float*)d_in[10];
    const float* fc2_b = (const float*)d_in[11];

    char* ws = (char*)d_ws;
    __bf16* P    = (__bf16*)(ws + OFF_P);
    float2* A    = (float2*)(ws + OFF_A);   // T1 / U2
    float2* Bb   = (float2*)(ws + OFF_B2);  // T2 / U1
    float2* Xf   = (float2*)(ws + OFF_XF);
    float2* Yf   = (float2*)(ws + OFF_YF);
    float*  part = (float*)(ws + OFF_XF);   // reuse Xf region (dead during k_fuse..k_bnfin)
    float2* gtw  = (float2*)(ws + OFF_TW);
    float*  bnp  = (float*)(ws + OFF_BNP);  // [4][64]
    float*  p2   = (float*)(ws + OFF_P2);   // [32][2 halves][2]

    k_twinit<<<1, 64, 0, stream>>>(gtw);
    k_lift<<<4096, 256, 0, stream>>>(x, fc0_w, fc0_b, P);

    for (int i = 0; i < 4; i++) {
        const float* bprev = (i == 0) ? nullptr : (bnp + (i - 1) * 64);
        int relu = (i > 0) ? 1 : 0;
        k_zfwd<<<2048, 256, 0, stream>>>(P, gtw, bprev, relu, A);
        k_dft2<<<4096, 256, 0, stream>>>(A, Bb, gtw, 0);
        k_dft2<<<1024, 256, 0, stream>>>(Bb, Xf, gtw, 1);
        k_specmul<<<2048, 128, 0, stream>>>(Xf, sw + (size_t)i * 4194304, Yf);
        k_xinv<<<1024, 256, 0, stream>>>(Yf, Bb);
        k_yinv<<<2048, 64, 0, stream>>>(Bb, A);
        k_fuse<<<4096, 256, 0, stream>>>(P, A, cw + i * 1024, cb + i * 32, bprev, relu, part);
        k_red<<<64, 256, 0, stream>>>(part, p2);
        k_bnfin<<<1, 32, 0, stream>>>(p2, gamma + i * 32, beta + i * 32, bnp + i * 64);
    }

    k_head<<<2048, 256, 0, stream>>>(P, bnp + 3 * 64, fc1_w, fc1_b, fc2_w, fc2_b, (float*)d_out);
}

// Round 4
// 697.846 us; speedup vs baseline: 1.8953x; 1.3620x over previous
//
#include <hip/hip_runtime.h>

#define TW_STEP 0.09817477042468103f  // 2*pi/64

typedef __bf16 bf16x8 __attribute__((ext_vector_type(8)));
typedef __bf16 bf16x4 __attribute__((ext_vector_type(4)));
typedef float  f32x4  __attribute__((ext_vector_type(4)));

// ---------------- workspace layout (bytes) ----------------
static constexpr size_t SZ_P   = (size_t)4*32*64*64*64*2;   // 67108864  field P [B][C][X][Y][Z] bf16
static constexpr size_t SZ_A   = (size_t)4*32*8*64*64*8;    // 33554432  T1 [b][c][kz][x][y] f2 / U2 [b][kz][x][y][o] f2
static constexpr size_t SZ_B2  = (size_t)4*32*8*16*64*8;    // 8388608   T2 / U1
static constexpr size_t SZ_XF  = (size_t)4*32*8*16*16*8;    // 2097152   Xf (also reused for bn partials)
static constexpr size_t OFF_P  = 0;
static constexpr size_t OFF_A  = OFF_P + SZ_P;
static constexpr size_t OFF_B2 = OFF_A + SZ_A;
static constexpr size_t OFF_XF = OFF_B2 + SZ_B2;
static constexpr size_t OFF_YF = OFF_XF + SZ_XF;
static constexpr size_t OFF_TW  = OFF_YF + SZ_XF;           // 64 float2
static constexpr size_t OFF_BNP = OFF_TW + 512;             // 4 layers * 64 floats

// ---------------- kernels ----------------

__global__ void k_twinit(float2* tw) {
    int t = threadIdx.x;
    if (t < 64) { float s, c; sincosf(TW_STEP * t, &s, &c); tw[t] = make_float2(c, s); }
}

// lift: x[B,X,Y,Z,3] -> P[b][w][x][y][z] (bf16)
__global__ __launch_bounds__(256) void k_lift(const float* __restrict__ x,
                                              const float* __restrict__ w,
                                              const float* __restrict__ bias,
                                              __bf16* __restrict__ P) {
    int v = blockIdx.x * 256 + threadIdx.x;      // 1048576 voxels
    int z = v & 63, y = (v >> 6) & 63, xx = (v >> 12) & 63, b = v >> 18;
    float i0 = x[(size_t)v * 3 + 0], i1 = x[(size_t)v * 3 + 1], i2 = x[(size_t)v * 3 + 2];
#pragma unroll
    for (int c = 0; c < 32; c++) {
        float val = bias[c] + w[c * 3 + 0] * i0 + w[c * 3 + 1] * i1 + w[c * 3 + 2] * i2;
        P[(size_t)(((b * 32 + c) * 64 + xx) * 64 + y) * 64 + z] = (__bf16)val;
    }
}

// forward z-DFT via Goertzel: P (with on-the-fly bn+relu) -> T1[b][c][kz][x][y]
__global__ __launch_bounds__(256) void k_zfwd(const __bf16* __restrict__ P,
                                              const float2* __restrict__ gtw,
                                              const float* __restrict__ bnp, int relu,
                                              float2* __restrict__ T1) {
    int g = blockIdx.x * 256 + threadIdx.x;      // 524288 = (b,c,x,y)
    int y = g & 63, x = (g >> 6) & 63, c = (g >> 12) & 31, b = g >> 17;
    float sc = 1.f, sh = 0.f;
    if (bnp) { sc = bnp[c]; sh = bnp[32 + c]; }
    const __bf16* row = P + (size_t)(((b * 32 + c) * 64 + x) * 64 + y) * 64;
    float ck[8], sk[8], c2[8];
#pragma unroll
    for (int k = 1; k < 8; k++) { float2 t = gtw[k]; ck[k] = t.x; sk[k] = t.y; c2[k] = 2.f * t.x; }
    float k0 = 0.f;
    float s1[8], s2[8];
#pragma unroll
    for (int k = 1; k < 8; k++) { s1[k] = 0.f; s2[k] = 0.f; }
#pragma unroll
    for (int q = 0; q < 8; q++) {
        bf16x8 v8 = ((const bf16x8*)row)[q];
#pragma unroll
        for (int j = 0; j < 8; j++) {
            float v = (float)v8[j] * sc + sh;
            if (relu) v = fmaxf(v, 0.f);
            k0 += v;
#pragma unroll
            for (int k = 1; k < 8; k++) {
                float s0 = fmaf(c2[k], s1[k], v - s2[k]);
                s2[k] = s1[k]; s1[k] = s0;
            }
        }
    }
    int ob = ((b * 32 + c) * 8) * 4096 + x * 64 + y;
    T1[ob] = make_float2(k0, 0.f);
    // X_k = e^{i theta} S63 - S62: Re = c*S63 - S62, Im = s*S63
#pragma unroll
    for (int k = 1; k < 8; k++)
        T1[ob + k * 4096] = make_float2(ck[k] * s1[k] - s2[k], sk[k] * s1[k]);
}

// forward 64->16 complex DFT along contiguous rows; 16 rows x 16 freqs per block.
__global__ __launch_bounds__(256) void k_dft2(const float2* __restrict__ in,
                                              float2* __restrict__ out,
                                              const float2* __restrict__ gtw,
                                              int mode) {
    int rb = blockIdx.x * 16;
    __shared__ float2 rows[16][65];
    int tid = threadIdx.x;
#pragma unroll
    for (int k = 0; k < 4; k++) {
        int idx = tid + k * 256;
        int r = idx >> 6, y = idx & 63;
        rows[r][y] = in[(size_t)(rb + r) * 64 + y];
    }
    __syncthreads();
    int ki = tid & 15, r = tid >> 4;
    int f = ki < 8 ? ki : ki + 48;
    float2 w = gtw[f];                            // (cos, sin) of +f*step
    float tc = 1.f, ts = 0.f;                     // e^{-i f theta y}
    float ar = 0.f, ai = 0.f;
#pragma unroll 8
    for (int y = 0; y < 64; y++) {
        float2 v = rows[r][y];
        ar = fmaf(v.x, tc, ar); ar = fmaf(-v.y, ts, ar);
        ai = fmaf(v.x, ts, ai); ai = fmaf(v.y, tc, ai);
        float nc = fmaf(tc, w.x, ts * w.y);
        float ns = fmaf(ts, w.x, -tc * w.y);
        tc = nc; ts = ns;
    }
    int rg = rb + r;
    if (mode == 0) out[(rg >> 6) * 1024 + ki * 64 + (rg & 63)] = make_float2(ar, ai);
    else           out[rg * 16 + ki] = make_float2(ar, ai);
}

// spectral multiply
__global__ __launch_bounds__(128) void k_specmul(const float2* __restrict__ Xf,
                                                 const float* __restrict__ swl,
                                                 float2* __restrict__ Yf) {
    int m = blockIdx.x;                           // 2048 = (kz,kyi,kxi)
    int kxi = m & 15, kyi = (m >> 4) & 15, kz = m >> 8;
    int corner = (kxi >= 8 ? 1 : 0) + (kyi >= 8 ? 2 : 0);
    int mx = kxi & 7, my = kyi & 7;
    __shared__ float2 wsd[1024];
    __shared__ float2 xfs[128];
    int tid = threadIdx.x;
    const float* wb = swl + (size_t)corner * 1048576 + mx * 128 + my * 16 + kz * 2;
    for (int idx = tid; idx < 1024; idx += 128) {
        int i = idx >> 5, o = idx & 31;
        const float* p = wb + (size_t)i * 32768 + o * 1024;
        wsd[idx] = make_float2(p[0], p[1]);
    }
    {
        int b = tid >> 5, i = tid & 31;
        xfs[tid] = Xf[(((b * 32 + i) * 8 + kz) * 16 + kyi) * 16 + kxi];
    }
    __syncthreads();
    int b = tid >> 5, o = tid & 31;
    float ar = 0.f, ai = 0.f;
#pragma unroll
    for (int i = 0; i < 32; i++) {
        float2 xv = xfs[b * 32 + i];
        float2 wv = wsd[i * 32 + o];
        ar += xv.x * wv.x - xv.y * wv.y;
        ai += xv.x * wv.y + xv.y * wv.x;
    }
    const float s = 1.0f / 262144.0f;
    Yf[(((b * 32 + o) * 8 + kz) * 16 + kyi) * 16 + kxi] = make_float2(ar * s, ai * s);
}

// inverse x: U1[b][o][kz][x][kyi] = sum_kx Yf * e^{+i}
__global__ __launch_bounds__(256) void k_xinv(const float2* __restrict__ Yf,
                                              float2* __restrict__ U1) {
    int blk = blockIdx.x;                         // 1024 = (b,o,kz)
    int kz = blk & 7, o = (blk >> 3) & 31, b = blk >> 8;
    __shared__ float2 yfs[16][17];
    __shared__ float2 tw[64];
    int tid = threadIdx.x;
    if (tid < 64) { float s, c; sincosf(TW_STEP * tid, &s, &c); tw[tid] = make_float2(c, s); }
    {
        int kyi = tid >> 4, kxi = tid & 15;
        yfs[kyi][kxi] = Yf[(size_t)((b * 32 + o) * 8 + kz) * 256 + tid];
    }
    __syncthreads();
    int base = ((b * 32 + o) * 8 + kz) * 1024;
#pragma unroll
    for (int r = 0; r < 4; r++) {
        int idx = tid + r * 256;
        int x = idx >> 4, kyi = idx & 15;
        float ar = 0.f, ai = 0.f;
#pragma unroll
        for (int kxi = 0; kxi < 16; kxi++) {
            int f = kxi < 8 ? kxi : kxi + 48;
            float2 t = tw[(f * x) & 63];
            float2 v = yfs[kyi][kxi];
            ar += v.x * t.x - v.y * t.y;
            ai += v.x * t.y + v.y * t.x;
        }
        U1[base + idx] = make_float2(ar, ai);
    }
}

// inverse y: U2[b][kz][x][y][o] = sum_ky U1 * e^{+i}
__global__ __launch_bounds__(64) void k_yinv(const float2* __restrict__ U1,
                                             float2* __restrict__ U2) {
    int blk = blockIdx.x;                         // 2048 = (b,kz,x)
    int x = blk & 63, kz = (blk >> 6) & 7, b = blk >> 9;
    __shared__ float2 u1s[32][16];
    __shared__ float2 tw[64];
    int tid = threadIdx.x;                        // 64 (= y)
    { float s, c; sincosf(TW_STEP * tid, &s, &c); tw[tid] = make_float2(c, s); }
#pragma unroll
    for (int j = 0; j < 8; j++) {
        int idx = tid + j * 64;
        int o = idx >> 4, kyi = idx & 15;
        u1s[o][kyi] = U1[((b * 32 + o) * 8 + kz) * 1024 + x * 16 + kyi];
    }
    __syncthreads();
    int y = tid;
    float tc[16], ts[16];
#pragma unroll
    for (int ki = 0; ki < 16; ki++) {
        int f = ki < 8 ? ki : ki + 48;
        float2 t = tw[(f * y) & 63];
        tc[ki] = t.x; ts[ki] = t.y;
    }
    float2 acc[32];
#pragma unroll
    for (int o = 0; o < 32; o++) {
        float ar = 0.f, ai = 0.f;
#pragma unroll
        for (int ki = 0; ki < 16; ki++) {
            float2 v = u1s[o][ki];
            ar += v.x * tc[ki] - v.y * ts[ki];
            ai += v.x * ts[ki] + v.y * tc[ki];
        }
        acc[o] = make_float2(ar, ai);
    }
    float2* rowp = U2 + (size_t)(((b * 8 + kz) * 64 + x) * 64 + y) * 32;
    float4* r4 = (float4*)rowp;
#pragma unroll
    for (int j = 0; j < 16; j++)
        r4[j] = make_float4(acc[2 * j].x, acc[2 * j].y, acc[2 * j + 1].x, acc[2 * j + 1].y);
}

// fused: P <- irfft_z(U2) + MFMA-pointwise(h) + cb ; emits bn partial sums.
// block = (b,x,yt): 4 y-rows x 64 z = 256 voxels, all 32 channels.
__global__ __launch_bounds__(256) void k_fuse(__bf16* __restrict__ P,
                                              const float2* __restrict__ U2,
                                              const float* __restrict__ cwl,
                                              const float* __restrict__ cbl,
                                              const float* __restrict__ bnp, int relu,
                                              float* __restrict__ part) {
    int blk = blockIdx.x;                         // 4096 = (b,x,yt)
    int yt = blk & 15, x = (blk >> 4) & 63, b = blk >> 10;
    int y0 = yt * 4;
    __shared__ __bf16 hs[256 * 40];               // [vox][ch] stride 40, 20480 B
    __shared__ float2 u2s[8][4][33];              // 8448 B
    __shared__ float2 twl[64];                    // 512 B
    __shared__ float sredS[4][32], sredQ[4][32];  // 1024 B
    int tid = threadIdx.x;
    int l = tid & 63, w = tid >> 6;
    if (tid < 64) { float s, c; sincosf(TW_STEP * tid, &s, &c); twl[tid] = make_float2(c, s); }

    int col = l & 15, kg = l >> 4;
    // B fragments: cw[o][c], o = nt*16+col, c = kg*8+j (row-major o x c)
    bf16x8 cwf[2];
    float cbv[2];
#pragma unroll
    for (int nt = 0; nt < 2; nt++) {
        int o = nt * 16 + col;
        const float4* p4 = (const float4*)(cwl + o * 32 + kg * 8);
        float4 q0 = p4[0], q1 = p4[1];
        cwf[nt][0] = (__bf16)q0.x; cwf[nt][1] = (__bf16)q0.y;
        cwf[nt][2] = (__bf16)q0.z; cwf[nt][3] = (__bf16)q0.w;
        cwf[nt][4] = (__bf16)q1.x; cwf[nt][5] = (__bf16)q1.y;
        cwf[nt][6] = (__bf16)q1.z; cwf[nt][7] = (__bf16)q1.w;
        cbv[nt] = cbl[o];
    }

    // stage hs (bn+relu applied): thread (c = tid>>3, j = tid&7) covers 4 y-rows x 8 z
    {
        int c = tid >> 3, j = tid & 7;
        float scb = 1.f, shb = 0.f;
        if (bnp) { scb = bnp[c]; shb = bnp[32 + c]; }
        const __bf16* src = P + ((size_t)((b * 32 + c) * 64 + x) * 64 + y0) * 64 + j * 8;
#pragma unroll
        for (int q = 0; q < 4; q++) {
            bf16x8 v8 = *(const bf16x8*)(src + q * 64);
#pragma unroll
            for (int jj = 0; jj < 8; jj++) {
                float v = (float)v8[jj];
                if (bnp) { v = fmaf(v, scb, shb); if (relu) v = fmaxf(v, 0.f); }
                hs[(q * 64 + j * 8 + jj) * 40 + c] = (__bf16)v;
            }
        }
    }
    // stage u2s
#pragma unroll
    for (int j2 = 0; j2 < 4; j2++) {
        int idx = tid + j2 * 256;                 // 1024 = kz*128 + yy*32 + o
        int kz = idx >> 7, rem = idx & 127, yy = rem >> 5, o = rem & 31;
        u2s[kz][yy][o] = U2[(size_t)(((b * 8 + kz) * 64 + x) * 64 + (y0 + yy)) * 32 + o];
    }
    __syncthreads();

    // MFMA pointwise: wave w owns y = y0+w (4 M-tiles of 16 z), 2 N-tiles of channels
    f32x4 acc[4][2];
#pragma unroll
    for (int i = 0; i < 4; i++) {
        bf16x8 a = *(const bf16x8*)&hs[((w * 4 + i) * 16 + col) * 40 + kg * 8];
#pragma unroll
        for (int nt = 0; nt < 2; nt++) {
            acc[i][nt] = (f32x4){0.f, 0.f, 0.f, 0.f};
            acc[i][nt] = __builtin_amdgcn_mfma_f32_16x16x32_bf16(a, cwf[nt], acc[i][nt], 0, 0, 0);
        }
    }

    // irfft-z add + bias + stats + store
    int q4 = l >> 4;
    float sacc[2] = {0.f, 0.f}, ssacc[2] = {0.f, 0.f};
#pragma unroll
    for (int nt = 0; nt < 2; nt++) {
        int o = nt * 16 + col;
        float u2r[8], u2i[8];
#pragma unroll
        for (int k = 0; k < 8; k++) { float2 v = u2s[k][w][o]; u2r[k] = v.x; u2i[k] = v.y; }
        __bf16* dstb = P + ((size_t)((b * 32 + o) * 64 + x) * 64 + (y0 + w)) * 64;
#pragma unroll
        for (int i = 0; i < 4; i++) {
            int z0 = i * 16 + q4 * 4;
            bf16x4 outv;
#pragma unroll
            for (int r = 0; r < 4; r++) {
                int z = z0 + r;
                float2 t1 = twl[z];
                float cp = t1.x, sp = t1.y;
                float v = fmaf(2.f * u2r[1], cp, u2r[0]);
                v = fmaf(-2.f * u2i[1], sp, v);
#pragma unroll
                for (int k = 2; k < 8; k++) {
                    float cn = cp * t1.x - sp * t1.y;
                    float sn = sp * t1.x + cp * t1.y;
                    v = fmaf(2.f * u2r[k], cn, v);
                    v = fmaf(-2.f * u2i[k], sn, v);
                    cp = cn; sp = sn;
                }
                float f = acc[i][nt][r] + cbv[nt] + v;
                sacc[nt] += f;
                ssacc[nt] = fmaf(f, f, ssacc[nt]);
                outv[r] = (__bf16)f;
            }
            *(bf16x4*)(dstb + z0) = outv;
        }
    }
    // reduce stats across the 4 row-groups (lanes sharing col)
#pragma unroll
    for (int nt = 0; nt < 2; nt++) {
        sacc[nt] += __shfl_xor(sacc[nt], 16, 64);
        sacc[nt] += __shfl_xor(sacc[nt], 32, 64);
        ssacc[nt] += __shfl_xor(ssacc[nt], 16, 64);
        ssacc[nt] += __shfl_xor(ssacc[nt], 32, 64);
    }
    if (l < 16) {
        sredS[w][col] = sacc[0]; sredS[w][16 + col] = sacc[1];
        sredQ[w][col] = ssacc[0]; sredQ[w][16 + col] = ssacc[1];
    }
    __syncthreads();
    if (tid < 32) {
        float S = sredS[0][tid] + sredS[1][tid] + sredS[2][tid] + sredS[3][tid];
        float SS = sredQ[0][tid] + sredQ[1][tid] + sredQ[2][tid] + sredQ[3][tid];
        part[((size_t)tid * 4096 + blk) * 2 + 0] = S;
        part[((size_t)tid * 4096 + blk) * 2 + 1] = SS;
    }
}

// one block per channel: reduce 4096 partials -> bn scale/shift
__global__ __launch_bounds__(256) void k_red2(const float* __restrict__ part,
                                              const float* __restrict__ gamma,
                                              const float* __restrict__ beta,
                                              float* __restrict__ bnp) {
    int c = blockIdx.x;
    int tid = threadIdx.x;
    const float2* pc = (const float2*)(part + (size_t)c * 8192);
    float s = 0.f, ss = 0.f;
#pragma unroll
    for (int q = 0; q < 16; q++) { float2 v = pc[tid * 16 + q]; s += v.x; ss += v.y; }
#pragma unroll
    for (int d = 32; d; d >>= 1) { s += __shfl_down(s, d, 64); ss += __shfl_down(ss, d, 64); }
    __shared__ float ws[8];
    if ((tid & 63) == 0) { ws[(tid >> 6) * 2] = s; ws[(tid >> 6) * 2 + 1] = ss; }
    __syncthreads();
    if (tid == 0) {
        double S = (double)ws[0] + ws[2] + ws[4] + ws[6];
        double SS = (double)ws[1] + ws[3] + ws[5] + ws[7];
        const double invN = 1.0 / 1048576.0;
        double mean = S * invN;
        double var = SS * invN - mean * mean;
        float scl = gamma[c] * rsqrtf((float)var + 1e-5f);
        bnp[c] = scl;
        bnp[32 + c] = beta[c] - (float)mean * scl;
    }
}

// head: bn (no relu) -> fc1(MFMA bf16) + relu -> fc2. Persistent per-block weights,
// 8 tiles of 64 voxels per block (2048 blocks).
__global__ __launch_bounds__(256) void k_head(const __bf16* __restrict__ P,
                                              const float* __restrict__ bnp,
                                              const float* __restrict__ w1,
                                              const float* __restrict__ b1,
                                              const float* __restrict__ w2,
                                              const float* __restrict__ b2,
                                              float* __restrict__ out) {
    __shared__ __bf16 hs[64 * 40];                // [vox][ch], stride 40
    int tid = threadIdx.x;
    int b = blockIdx.x >> 9;                      // 512 blocks per batch
    int r0 = (blockIdx.x & 511) * 512;            // 512 voxels per block
    int l = tid & 63;
    int w = tid >> 6;
    int col = l & 15, kg = l >> 4;

    bf16x8 bfr[8];
    float b1v[8], w2v[8];
    {
        const float4* w1v = (const float4*)w1;
#pragma unroll
        for (int nt = 0; nt < 8; nt++) {
            int f = nt * 16 + col;
            float4 q0 = w1v[f * 8 + kg * 2];
            float4 q1 = w1v[f * 8 + kg * 2 + 1];
            bfr[nt][0] = (__bf16)q0.x; bfr[nt][1] = (__bf16)q0.y;
            bfr[nt][2] = (__bf16)q0.z; bfr[nt][3] = (__bf16)q0.w;
            bfr[nt][4] = (__bf16)q1.x; bfr[nt][5] = (__bf16)q1.y;
            bfr[nt][6] = (__bf16)q1.z; bfr[nt][7] = (__bf16)q1.w;
            b1v[nt] = b1[f]; w2v[nt] = w2[f];
        }
    }
    float b2v = b2[0];
    int sc_c = tid & 31, sc_j = tid >> 5;
    float scb = bnp[sc_c], shb = bnp[32 + sc_c];
    const __bf16* srcb = P + (size_t)(b * 32 + sc_c) * 262144 + r0 + sc_j * 8;

    for (int t = 0; t < 8; t++) {
        {
            bf16x8 v8 = *(const bf16x8*)(srcb + t * 64);
#pragma unroll
            for (int jj = 0; jj < 8; jj++)
                hs[(sc_j * 8 + jj) * 40 + sc_c] = (__bf16)((float)v8[jj] * scb + shb);
        }
        __syncthreads();
        bf16x8 a = *(const bf16x8*)&hs[(w * 16 + (l & 15)) * 40 + kg * 8];
        f32x4 acc[8];
#pragma unroll
        for (int nt = 0; nt < 8; nt++) {
            acc[nt] = (f32x4){0.f, 0.f, 0.f, 0.f};
            acc[nt] = __builtin_amdgcn_mfma_f32_16x16x32_bf16(a, bfr[nt], acc[nt], 0, 0, 0);
        }
        float s[4] = {0.f, 0.f, 0.f, 0.f};
#pragma unroll
        for (int nt = 0; nt < 8; nt++) {
#pragma unroll
            for (int r = 0; r < 4; r++) {
                float val = fmaxf(acc[nt][r] + b1v[nt], 0.f);
                s[r] = fmaf(w2v[nt], val, s[r]);
            }
        }
#pragma unroll
        for (int r = 0; r < 4; r++) {
            s[r] += __shfl_xor(s[r], 1, 64);
            s[r] += __shfl_xor(s[r], 2, 64);
            s[r] += __shfl_xor(s[r], 4, 64);
            s[r] += __shfl_xor(s[r], 8, 64);
        }
        if ((l & 15) == 0) {
            int vb = b * 262144 + r0 + t * 64 + w * 16 + (l >> 4) * 4;
#pragma unroll
            for (int r = 0; r < 4; r++) out[vb + r] = s[r] + b2v;
        }
        __syncthreads();
    }
}

// ---------------- launcher ----------------
extern "C" void kernel_launch(void* const* d_in, const int* in_sizes, int n_in,
                              void* d_out, int out_size, void* d_ws, size_t ws_size,
                              hipStream_t stream) {
    const float* x     = (const float*)d_in[0];
    const float* fc0_w = (const float*)d_in[1];
    const float* fc0_b = (const float*)d_in[2];
    const float* sw    = (const float*)d_in[3];
    const float* cw    = (const float*)d_in[4];
    const float* cb    = (const float*)d_in[5];
    const float* gamma = (const float*)d_in[6];
    const float* beta  = (const float*)d_in[7];
    const float* fc1_w = (const float*)d_in[8];
    const float* fc1_b = (const float*)d_in[9];
    const float* fc2_w = (const float*)d_in[10];
    const float* fc2_b = (const float*)d_in[11];

    char* ws = (char*)d_ws;
    __bf16* P    = (__bf16*)(ws + OFF_P);
    float2* A    = (float2*)(ws + OFF_A);   // T1 / U2
    float2* Bb   = (float2*)(ws + OFF_B2);  // T2 / U1
    float2* Xf   = (float2*)(ws + OFF_XF);
    float2* Yf   = (float2*)(ws + OFF_YF);
    float*  part = (float*)(ws + OFF_XF);   // reuse Xf region (dead during k_fuse..k_red2)
    float2* gtw  = (float2*)(ws + OFF_TW);
    float*  bnp  = (float*)(ws + OFF_BNP);  // [4][64]

    k_twinit<<<1, 64, 0, stream>>>(gtw);
    k_lift<<<4096, 256, 0, stream>>>(x, fc0_w, fc0_b, P);

    for (int i = 0; i < 4; i++) {
        const float* bprev = (i == 0) ? nullptr : (bnp + (i - 1) * 64);
        int relu = (i > 0) ? 1 : 0;
        k_zfwd<<<2048, 256, 0, stream>>>(P, gtw, bprev, relu, A);
        k_dft2<<<4096, 256, 0, stream>>>(A, Bb, gtw, 0);
        k_dft2<<<1024, 256, 0, stream>>>(Bb, Xf, gtw, 1);
        k_specmul<<<2048, 128, 0, stream>>>(Xf, sw + (size_t)i * 4194304, Yf);
        k_xinv<<<1024, 256, 0, stream>>>(Yf, Bb);
        k_yinv<<<2048, 64, 0, stream>>>(Bb, A);
        k_fuse<<<4096, 256, 0, stream>>>(P, A, cw + i * 1024, cb + i * 32, bprev, relu, part);
        k_red2<<<32, 256, 0, stream>>>(part, gamma + i * 32, beta + i * 32, bnp + i * 64);
    }

    k_head<<<2048, 256, 0, stream>>>(P, bnp + 3 * 64, fc1_w, fc1_b, fc2_w, fc2_b, (float*)d_out);
}